// Round 6
// baseline (114.748 us; speedup 1.0000x reference)
//
#include <hip/hip_runtime.h>
#include <hip/hip_bf16.h>
#include <stdint.h>

// C = (B,16,16): diag (k,k)=sigmoid(x·Wd[k]+bd[k]); off (i,j)=-softplus(x·Wo[r]+bo[r])
// Permuted GEMM out[b][c], c=i*16+j. M=65536 N=256 K=1024, bf16 MFMA 16x16x32.
// R6: fixed T3+T4 pipeline. BM=128, BK=32, 512 thr (8 waves, 2Mx4N).
// LDS: A 2x8K + B 4x16K = 80KB (2 blocks/CU). Step t: ds_read A(t),B(t) ->
// issue B(t+2) glds + x(t+2) reg loads -> MFMA -> vmcnt(4) (retires B(t+1),x(t+1);
// leaves B(t+2),x(t+2) in flight) -> pack x(t+1)->A(t+1) -> lgkmcnt(0), s_barrier.
// x regs parity-double-buffered, all slot indices compile-time (4x unroll).

typedef __bf16 bf16x8 __attribute__((ext_vector_type(8)));
typedef float f32x4 __attribute__((ext_vector_type(4)));

#define THREADS 512
#define BM 128
#define KSTEPS 32
#define WIMG 16384                 // per-K-step B image: 256 cols x 32 k x 2B
#define WBYTES (WIMG * KSTEPS)     // 512 KiB

#define A_SZ 8192
#define B_OFF 16384
#define B_SZ 16384
#define SMEM_SZ 81920              // 80 KiB -> 2 blocks/CU

__device__ __forceinline__ unsigned bf_rtne(unsigned u) {
  return (u + 0x7fffu + ((u >> 16) & 1u)) >> 16;
}
__device__ __forceinline__ unsigned pack2(float lo, float hi) {
  return bf_rtne(__float_as_uint(lo)) | (bf_rtne(__float_as_uint(hi)) << 16);
}

__device__ __forceinline__ void gload_lds16(const void* g, void* l) {
  __builtin_amdgcn_global_load_lds(
      (const __attribute__((address_space(1))) unsigned int*)g,
      (__attribute__((address_space(3))) unsigned int*)l, 16, 0, 0);
}

// B image per K-step: byte(c,k) = (c*64 + k*2) ^ (((c>>1)&3)<<4)
__global__ void prep_kernel(const float* __restrict__ Wd, const float* __restrict__ bd,
                            const float* __restrict__ Wo, const float* __restrict__ bo,
                            char* __restrict__ wbuf, float* __restrict__ bias) {
  const int c = blockIdx.x;    // 0..255 output col
  const int t = threadIdx.x;   // 0..255, 4 consecutive k each
  const int i = c >> 4, j = c & 15;
  const float* src;
  float b;
  if (i == j) { src = Wd + i * 1024; b = bd[i]; }
  else { int r = i * 15 + (j < i ? j : j - 1); src = Wo + r * 1024; b = bo[r]; }
  if (t == 0) bias[c] = b;
  const int kk = t * 4;
  const int img = kk >> 5, k5 = kk & 31;
  float4 v = *reinterpret_cast<const float4*>(src + kk);
  uint2 h;
  h.x = pack2(v.x, v.y);
  h.y = pack2(v.z, v.w);
  const unsigned off = (unsigned)((c * 64 + k5 * 2) ^ (((c >> 1) & 3) << 4));
  *reinterpret_cast<uint2*>(wbuf + img * WIMG + off) = h;
}

__global__ __launch_bounds__(THREADS, 4) void cap_main(
    const float* __restrict__ x, const char* __restrict__ wbuf,
    const float* __restrict__ bias, float* __restrict__ out) {
  __shared__ char smem[SMEM_SZ];

  const int tid = threadIdx.x;
  const int wid = tid >> 6;
  const int lane = tid & 63;
  const int l15 = lane & 15;
  const int l4 = lane >> 4;
  const int wm = wid >> 2;  // 0..1 -> 64 rows each
  const int wn = wid & 3;   // 0..3 -> 64 cols each

  const size_t blkRow = (size_t)blockIdx.x * BM;

  // A staging: thread owns 8 consecutive floats of the 128x32 step slice
  const int ar = tid >> 2;             // row 0..127
  const int akc = tid & 3;             // 16B chunk 0..3
  const float* xs = x + (blkRow + (size_t)ar) * 1024 + akc * 8;
  const unsigned awz = (unsigned)((ar * 64 + akc * 16) ^ (((ar >> 1) & 3) << 4));

  // fragment bases
  const unsigned sw = (unsigned)(((l15 >> 1) & 3) << 4);
  const unsigned abase = (unsigned)(((wm * 64 + l15) * 64 + l4 * 16) ^ sw);  // + m*1024
  const unsigned bbase = (unsigned)(((wn * 64 + l15) * 64 + l4 * 16) ^ sw);  // + n*1024

  f32x4 acc[4][4];
#pragma unroll
  for (int m = 0; m < 4; ++m)
#pragma unroll
    for (int n = 0; n < 4; ++n) acc[m][n] = (f32x4){0.f, 0.f, 0.f, 0.f};

  float4 xr[2][2];  // parity-indexed x prefetch regs (always static indices)

  // ---- prologue ----
  // issue order: x(0), B(0), B(1), x(1)  ->  vmcnt(4) retires x(0)+B(0),
  // leaves B(1)+x(1) in flight == steady state entering t=0.
  float4 x0a = *reinterpret_cast<const float4*>(xs);
  float4 x0b = *reinterpret_cast<const float4*>(xs + 4);
  gload_lds16(wbuf + tid * 16, smem + B_OFF + tid * 16);
  gload_lds16(wbuf + 8192 + tid * 16, smem + B_OFF + 8192 + tid * 16);
  gload_lds16(wbuf + WIMG + tid * 16, smem + B_OFF + B_SZ + tid * 16);
  gload_lds16(wbuf + WIMG + 8192 + tid * 16, smem + B_OFF + B_SZ + 8192 + tid * 16);
  xr[1][0] = *reinterpret_cast<const float4*>(xs + 32);
  xr[1][1] = *reinterpret_cast<const float4*>(xs + 36);
  asm volatile("s_waitcnt vmcnt(4)" ::: "memory");
  {
    uint4 w;
    w.x = pack2(x0a.x, x0a.y); w.y = pack2(x0a.z, x0a.w);
    w.z = pack2(x0b.x, x0b.y); w.w = pack2(x0b.z, x0b.w);
    *reinterpret_cast<uint4*>(smem + awz) = w;  // A(0) -> slot 0
  }
  asm volatile("s_waitcnt lgkmcnt(0)" ::: "memory");
  __builtin_amdgcn_s_barrier();

  for (int kk = 0; kk < KSTEPS / 4; ++kk) {
#pragma unroll
    for (int i = 0; i < 4; ++i) {
      const int t = kk * 4 + i;
      const char* Ac = smem + (i & 1) * A_SZ;            // A(t), t%2
      const char* Bc = smem + B_OFF + i * B_SZ;          // B(t), t%4
      char* Aw = smem + ((i + 1) & 1) * A_SZ;            // A(t+1)
      char* Bw = smem + B_OFF + ((i + 2) & 3) * B_SZ;    // B(t+2)

      // P1: fragment ds_reads
      bf16x8 af[4], bfr[4];
#pragma unroll
      for (int m = 0; m < 4; ++m)
        af[m] = *reinterpret_cast<const bf16x8*>(Ac + abase + m * 1024);
#pragma unroll
      for (int n = 0; n < 4; ++n)
        bfr[n] = *reinterpret_cast<const bf16x8*>(Bc + bbase + n * 1024);

      // P2: issue B(t+2) glds then x(t+2) reg loads (clamped tail, uniform counts)
      const int tB = (t + 2 < KSTEPS) ? t + 2 : KSTEPS - 1;
      const char* wsp = wbuf + tB * WIMG;
      gload_lds16(wsp + tid * 16, Bw + tid * 16);
      gload_lds16(wsp + 8192 + tid * 16, Bw + 8192 + tid * 16);
      const float* xsp = xs + tB * 32;
      xr[i & 1][0] = *reinterpret_cast<const float4*>(xsp);
      xr[i & 1][1] = *reinterpret_cast<const float4*>(xsp + 4);

      // P3: MFMA (lgkm waits auto-inserted for frags)
#pragma unroll
      for (int m = 0; m < 4; ++m)
#pragma unroll
        for (int n = 0; n < 4; ++n)
          acc[m][n] = __builtin_amdgcn_mfma_f32_16x16x32_bf16(af[m], bfr[n], acc[m][n], 0, 0, 0);

      // P4: counted wait — retires B(t+1)+x(t+1); B(t+2)+x(t+2) stay in flight
      asm volatile("s_waitcnt vmcnt(4)" ::: "memory");

      // P5: pack x(t+1) -> A(t+1)
      {
        const float4 pa = xr[(i + 1) & 1][0];
        const float4 pb = xr[(i + 1) & 1][1];
        uint4 w;
        w.x = pack2(pa.x, pa.y); w.y = pack2(pa.z, pa.w);
        w.z = pack2(pb.x, pb.y); w.w = pack2(pb.z, pb.w);
        *reinterpret_cast<uint4*>(Aw + awz) = w;
      }

      // P6: LDS visibility + barrier (no vmcnt drain)
      asm volatile("s_waitcnt lgkmcnt(0)" ::: "memory");
      __builtin_amdgcn_s_barrier();
    }
  }

  // ---- epilogue: activation -> LDS transpose (1040B pitch) -> row stores ----
  float bs[4];
#pragma unroll
  for (int n = 0; n < 4; ++n) bs[n] = bias[wn * 64 + n * 16 + l15];

  const int rr2 = tid >> 5;            // 0..15 read-back row
  const int co = (tid & 31) * 8;       // read-back col (floats)
  const char* rdp = smem + rr2 * 1040 + co * 4;

  __syncthreads();  // drain tail loads once; enter epilogue clean

#pragma unroll
  for (int p = 0; p < 8; ++p) {
    if ((wid >> 2) == (p >> 2)) {
      const int m = p & 3;
#pragma unroll
      for (int n = 0; n < 4; ++n) {
        const int col = wn * 64 + n * 16 + l15;
        const bool diag = (col % 17) == 0;
#pragma unroll
        for (int j2 = 0; j2 < 4; ++j2) {
          const int rr = l4 * 4 + j2;
          float v = acc[m][n][j2] + bs[n];
          float e = __expf(-fabsf(v));
          float sig = (v >= 0.f) ? 1.f / (1.f + e) : e / (1.f + e);
          float sp = fmaxf(v, 0.f) + __logf(1.f + e);
          *reinterpret_cast<float*>(smem + rr * 1040 + col * 4) = diag ? sig : -sp;
        }
      }
    }
    __syncthreads();
    float4 o0 = *reinterpret_cast<const float4*>(rdp);
    float4 o1 = *reinterpret_cast<const float4*>(rdp + 16);
    float* orow = out + (blkRow + (size_t)(p * 16 + rr2)) * 256 + co;
    *reinterpret_cast<float4*>(orow) = o0;
    *reinterpret_cast<float4*>(orow + 4) = o1;
    __syncthreads();
  }
}

extern "C" void kernel_launch(void* const* d_in, const int* in_sizes, int n_in,
                              void* d_out, int out_size, void* d_ws, size_t ws_size,
                              hipStream_t stream) {
  const float* x = (const float*)d_in[0];
  const float* Wd = (const float*)d_in[1];
  const float* bd = (const float*)d_in[2];
  const float* Wo = (const float*)d_in[3];
  const float* bo = (const float*)d_in[4];
  float* out = (float*)d_out;
  char* wbuf = (char*)d_ws;                  // 512 KiB weight image
  float* bias = (float*)(wbuf + WBYTES);     // 1 KiB bias

  prep_kernel<<<dim3(256), dim3(256), 0, stream>>>(Wd, bd, Wo, bo, wbuf, bias);
  cap_main<<<dim3(512), dim3(THREADS), 0, stream>>>(x, wbuf, bias, out);
}

// Round 7
// 109.238 us; speedup vs baseline: 1.0504x; 1.0504x over previous
//
#include <hip/hip_runtime.h>
#include <hip/hip_bf16.h>
#include <stdint.h>

// C = (B,16,16): diag (k,k)=sigmoid(x·Wd[k]+bd[k]); off (i,j)=-softplus(x·Wo[r]+bo[r])
// Permuted GEMM out[b][c], c=i*16+j. M=65536 N=256 K=1024, bf16 MFMA 16x16x32.
// R7: A never touches LDS. Each wave owns 16 rows x 256 cols; A-fragments load
// straight from global (coalesced) into regs, pack fp32->bf16, MFMA. Only B is
// LDS-staged (K=64 chunks, dbuf, gload_lds from pre-swizzled L2 image). One
// barrier per chunk; vmcnt(4) leaves the A prefetch in flight across it.

typedef __bf16 bf16x8 __attribute__((ext_vector_type(8)));
typedef float f32x4 __attribute__((ext_vector_type(4)));

#define THREADS 512
#define BM 128
#define NCHUNK 16                  // K chunks of 64
#define CIMG 32768                 // per-chunk B image: 256 cols x 64 k x 2B
#define WBYTES (CIMG * NCHUNK)     // 512 KiB

__device__ __forceinline__ unsigned bf_rtne(unsigned u) {
  return (u + 0x7fffu + ((u >> 16) & 1u)) >> 16;
}
__device__ __forceinline__ unsigned pack2(float lo, float hi) {
  return bf_rtne(__float_as_uint(lo)) | (bf_rtne(__float_as_uint(hi)) << 16);
}

__device__ __forceinline__ void gload_lds16(const void* g, void* l) {
  __builtin_amdgcn_global_load_lds(
      (const __attribute__((address_space(1))) unsigned int*)g,
      (__attribute__((address_space(3))) unsigned int*)l, 16, 0, 0);
}

// B image per chunk: byte(c,k6) = (c*128 + k6*2) ^ ((c&7)<<4)  (col stride 128B)
__global__ void prep_kernel(const float* __restrict__ Wd, const float* __restrict__ bd,
                            const float* __restrict__ Wo, const float* __restrict__ bo,
                            char* __restrict__ wbuf, float* __restrict__ bias) {
  const int c = blockIdx.x;    // 0..255 output col
  const int t = threadIdx.x;   // 0..255, 4 consecutive k each
  const int i = c >> 4, j = c & 15;
  const float* src;
  float b;
  if (i == j) { src = Wd + i * 1024; b = bd[i]; }
  else { int r = i * 15 + (j < i ? j : j - 1); src = Wo + r * 1024; b = bo[r]; }
  if (t == 0) bias[c] = b;
  const int kk = t * 4;
  const int chunk = kk >> 6, k6 = kk & 63;
  float4 v = *reinterpret_cast<const float4*>(src + kk);
  uint2 h;
  h.x = pack2(v.x, v.y);
  h.y = pack2(v.z, v.w);
  const unsigned off = (unsigned)((c * 128 + k6 * 2) ^ ((c & 7) << 4));
  *reinterpret_cast<uint2*>(wbuf + chunk * CIMG + off) = h;
}

__device__ __forceinline__ bf16x8 packfrag(const float4& a, const float4& b) {
  uint4 u;
  u.x = pack2(a.x, a.y); u.y = pack2(a.z, a.w);
  u.z = pack2(b.x, b.y); u.w = pack2(b.z, b.w);
  return *reinterpret_cast<bf16x8*>(&u);
}

__global__ __launch_bounds__(THREADS, 4) void cap_main(
    const float* __restrict__ x, const char* __restrict__ wbuf,
    const float* __restrict__ bias, float* __restrict__ out) {
  __shared__ char smem[65536];  // B dbuf: 2 x 32 KB; epilogue reuses 33.3 KB

  const int tid = threadIdx.x;
  const int wid = tid >> 6;
  const int lane = tid & 63;
  const int l15 = lane & 15;
  const int l4 = lane >> 4;

  const size_t blkRow = (size_t)blockIdx.x * BM;

  // A-fragment source: row = blkRow + wid*16 + l15, k base l4*8 (+chunk*64 +ks*32)
  const float* xrow = x + (blkRow + (size_t)(wid * 16 + l15)) * 1024 + l4 * 8;

  // B fragment per-lane bases (within a 32 KB chunk buffer)
  const unsigned swz = (unsigned)((l15 & 7) << 4);
  const unsigned ds0 = (unsigned)(l15 * 128 + ((l4 * 16) ^ swz));        // ks=0, +n*2048
  const unsigned ds1 = (unsigned)(l15 * 128 + ((64 + l4 * 16) ^ swz));   // ks=1, +n*2048

  f32x4 acc[16];
#pragma unroll
  for (int n = 0; n < 16; ++n) acc[n] = (f32x4){0.f, 0.f, 0.f, 0.f};

  float4 p0, p1, p2, p3;

  // ---- prologue: B(0) glds -> buf0; A(0) -> regs; drain; barrier ----
#pragma unroll
  for (int i = 0; i < 4; ++i)
    gload_lds16(wbuf + i * 8192 + tid * 16, smem + i * 8192 + tid * 16);
  asm volatile("" ::: "memory");
  p0 = *reinterpret_cast<const float4*>(xrow);
  p1 = *reinterpret_cast<const float4*>(xrow + 4);
  p2 = *reinterpret_cast<const float4*>(xrow + 32);
  p3 = *reinterpret_cast<const float4*>(xrow + 36);
  asm volatile("s_waitcnt vmcnt(0)" ::: "memory");
  __builtin_amdgcn_s_barrier();

#define COMPUTE(BUF, AF0, AF1)                                                  \
  {                                                                             \
    _Pragma("unroll") for (int ks = 0; ks < 2; ++ks) {                          \
      const char* bp = (BUF) + (ks ? ds1 : ds0);                                \
      const bf16x8 a = ks ? (AF1) : (AF0);                                      \
      _Pragma("unroll") for (int n0 = 0; n0 < 16; n0 += 4) {                    \
        bf16x8 b0 = *reinterpret_cast<const bf16x8*>(bp + (n0 + 0) * 2048);     \
        bf16x8 b1 = *reinterpret_cast<const bf16x8*>(bp + (n0 + 1) * 2048);     \
        bf16x8 b2 = *reinterpret_cast<const bf16x8*>(bp + (n0 + 2) * 2048);     \
        bf16x8 b3 = *reinterpret_cast<const bf16x8*>(bp + (n0 + 3) * 2048);     \
        acc[n0 + 0] = __builtin_amdgcn_mfma_f32_16x16x32_bf16(a, b0, acc[n0 + 0], 0, 0, 0); \
        acc[n0 + 1] = __builtin_amdgcn_mfma_f32_16x16x32_bf16(a, b1, acc[n0 + 1], 0, 0, 0); \
        acc[n0 + 2] = __builtin_amdgcn_mfma_f32_16x16x32_bf16(a, b2, acc[n0 + 2], 0, 0, 0); \
        acc[n0 + 3] = __builtin_amdgcn_mfma_f32_16x16x32_bf16(a, b3, acc[n0 + 3], 0, 0, 0); \
      }                                                                         \
    }                                                                           \
  }

  for (int c = 0; c < NCHUNK - 1; ++c) {
    const char* Bc = smem + (c & 1) * 32768;
    char* Bn = smem + ((c + 1) & 1) * 32768;

    // pack A(c) (true-dependence wait; cover = previous chunk)
    bf16x8 af0 = packfrag(p0, p1);
    bf16x8 af1 = packfrag(p2, p3);

    // issue B(c+1) gloads FIRST, then A(c+1) reg loads (order pinned)
    const char* wsp = wbuf + (c + 1) * CIMG;
#pragma unroll
    for (int i = 0; i < 4; ++i)
      gload_lds16(wsp + i * 8192 + tid * 16, Bn + i * 8192 + tid * 16);
    asm volatile("" ::: "memory");
    const float* xp = xrow + (c + 1) * 64;
    p0 = *reinterpret_cast<const float4*>(xp);
    p1 = *reinterpret_cast<const float4*>(xp + 4);
    p2 = *reinterpret_cast<const float4*>(xp + 32);
    p3 = *reinterpret_cast<const float4*>(xp + 36);
    asm volatile("" ::: "memory");

    // MFMA phase: LDS reads + register A only
    COMPUTE(Bc, af0, af1);

    // retire this wave's B(c+1) gloads (oldest 4); A(c+1) stays in flight
    asm volatile("s_waitcnt vmcnt(4)" ::: "memory");
    asm volatile("s_waitcnt lgkmcnt(0)" ::: "memory");
    __builtin_amdgcn_s_barrier();
  }

  // last chunk (no prefetch)
  {
    bf16x8 af0 = packfrag(p0, p1);
    bf16x8 af1 = packfrag(p2, p3);
    const char* Bc = smem + ((NCHUNK - 1) & 1) * 32768;
    COMPUTE(Bc, af0, af1);
  }
  asm volatile("s_waitcnt lgkmcnt(0)" ::: "memory");
  __builtin_amdgcn_s_barrier();

  // ---- epilogue: 4 passes x 2 wave-stripes; LDS transpose (1040B pitch) ----
  const int err = tid >> 4;           // 0..31 read-back row
  const int ec = tid & 15;            // 16-float col group
  const char* rdp = smem + err * 1040 + ec * 64;

#pragma unroll
  for (int p = 0; p < 4; ++p) {
    if ((wid >> 1) == p) {
      const int sr = (wid & 1) * 16;  // stripe base row in LDS
#pragma unroll
      for (int n = 0; n < 16; ++n) {
        const int col = n * 16 + l15;
        const float bv = bias[col];
        const bool diag = (col % 17) == 0;
#pragma unroll
        for (int j2 = 0; j2 < 4; ++j2) {
          float v = acc[n][j2] + bv;
          float e = __expf(-fabsf(v));
          float sig = (v >= 0.f) ? 1.f / (1.f + e) : e / (1.f + e);
          float sp = fmaxf(v, 0.f) + __logf(1.f + e);
          *reinterpret_cast<float*>(smem + (sr + l4 * 4 + j2) * 1040 + col * 4) =
              diag ? sig : -sp;
        }
      }
    }
    __syncthreads();
    float4 o0 = *reinterpret_cast<const float4*>(rdp);
    float4 o1 = *reinterpret_cast<const float4*>(rdp + 16);
    float4 o2 = *reinterpret_cast<const float4*>(rdp + 32);
    float4 o3 = *reinterpret_cast<const float4*>(rdp + 48);
    float* orow = out + (blkRow + (size_t)(p * 32 + err)) * 256 + ec * 16;
    *reinterpret_cast<float4*>(orow) = o0;
    *reinterpret_cast<float4*>(orow + 4) = o1;
    *reinterpret_cast<float4*>(orow + 8) = o2;
    *reinterpret_cast<float4*>(orow + 12) = o3;
    __syncthreads();
  }
}

extern "C" void kernel_launch(void* const* d_in, const int* in_sizes, int n_in,
                              void* d_out, int out_size, void* d_ws, size_t ws_size,
                              hipStream_t stream) {
  const float* x = (const float*)d_in[0];
  const float* Wd = (const float*)d_in[1];
  const float* bd = (const float*)d_in[2];
  const float* Wo = (const float*)d_in[3];
  const float* bo = (const float*)d_in[4];
  float* out = (float*)d_out;
  char* wbuf = (char*)d_ws;                  // 512 KiB weight image
  float* bias = (float*)(wbuf + WBYTES);     // 1 KiB bias

  prep_kernel<<<dim3(256), dim3(256), 0, stream>>>(Wd, bd, Wo, bo, wbuf, bias);
  cap_main<<<dim3(512), dim3(THREADS), 0, stream>>>(x, wbuf, bias, out);
}